// Round 17
// baseline (133.884 us; speedup 1.0000x reference)
//
#include <hip/hip_runtime.h>

typedef _Float16 f16;
typedef _Float16 f16x8 __attribute__((ext_vector_type(8)));
typedef _Float16 f16x4 __attribute__((ext_vector_type(4)));
typedef _Float16 f16x2 __attribute__((ext_vector_type(2)));
typedef float f32x4 __attribute__((ext_vector_type(4)));

#define MFMA(a, b, c) __builtin_amdgcn_mfma_f32_16x16x32_f16(a, b, c, 0, 0, 0)
#define PKRTZ(a, b) __builtin_bit_cast(f16x2, __builtin_amdgcn_cvt_pkrtz(a, b))
#define BARRAW() do { asm volatile("" ::: "memory"); __builtin_amdgcn_s_barrier(); asm volatile("" ::: "memory"); } while (0)
#define WAITLGKM0() do { asm volatile("s_waitcnt lgkmcnt(0)" ::: "memory"); __builtin_amdgcn_sched_barrier(0); } while (0)

__device__ __forceinline__ void gload16(const void* g, void* l) {
  __builtin_amdgcn_global_load_lds((const __attribute__((address_space(1))) char*)g,
                                   (__attribute__((address_space(3))) char*)l, 16, 0, 0);
}

// B=2, T=2048, D=1024, H=16, DH=64

// ---------- prep: z<4: transpose+convert weight z; z==4: fp32->fp16 hidden ----------
__global__ __launch_bounds__(256) void k_prep(const float* __restrict__ hid,
                                              const float* __restrict__ w0, const float* __restrict__ w1,
                                              const float* __restrict__ w2, const float* __restrict__ w3,
                                              f16* __restrict__ aH, f16* __restrict__ wt) {
  int z = blockIdx.z;
  int t = threadIdx.x;
  if (z == 4) {
    int base = (blockIdx.y * 16 + blockIdx.x) * 256 + t;
#pragma unroll
    for (int j = 0; j < 16; j++) {               // 65536 thr x 16 = 1M float4 = full input
      int i = base + j * 65536;
      float4 v = ((const float4*)hid)[i];
      f16x4 h; h[0] = (f16)v.x; h[1] = (f16)v.y; h[2] = (f16)v.z; h[3] = (f16)v.w;
      ((f16x4*)aH)[i] = h;
    }
    return;
  }
  const float* w = z == 0 ? w0 : z == 1 ? w1 : z == 2 ? w2 : w3;
  f16* dst = wt + (size_t)z * 1024 * 1024;
  __shared__ float tile[64][65];
  int k0 = blockIdx.x * 64, n0 = blockIdx.y * 64;
  int cr = t >> 4, cc = (t & 15) * 4;
#pragma unroll
  for (int p = 0; p < 4; p++) {
    int r = cr + p * 16;
    float4 v = *(const float4*)&w[(size_t)(k0 + r) * 1024 + n0 + cc];
    tile[r][cc + 0] = v.x; tile[r][cc + 1] = v.y; tile[r][cc + 2] = v.z; tile[r][cc + 3] = v.w;
  }
  __syncthreads();
#pragma unroll
  for (int p = 0; p < 4; p++) {
    int nn = cr + p * 16;
    f16x4 h;
    h[0] = (f16)tile[cc + 0][nn]; h[1] = (f16)tile[cc + 1][nn];
    h[2] = (f16)tile[cc + 2][nn]; h[3] = (f16)tile[cc + 3][nn];
    *(f16x4*)&dst[(size_t)(n0 + nn) * 1024 + k0 + cc] = h;
  }
}

// ---------- QKV GEMM: 256x256 tile, BK=64, 8-phase counted-vmcnt pipeline (R9) ----------
__global__ __launch_bounds__(512, 1) void k_gemm_qkv(const f16* __restrict__ A, const f16* __restrict__ wt,
                                                     const float* __restrict__ bq, const float* __restrict__ bk,
                                                     const float* __restrict__ bv,
                                                     f16* __restrict__ q, f16* __restrict__ k, f16* __restrict__ v) {
  __shared__ f16 L[8][128 * 64];
  const int t = threadIdx.x;
  const int lane = t & 63, wid = t >> 6;
  const int lr = lane & 15, lg = lane >> 4;
  const int wm = wid >> 2, wn = wid & 3;
  const int lrow = lane >> 3;
  const int cb = (((lane & 7) ^ lrow) << 4);
  const int bid = blockIdx.x;
  const int x = bid & 7, loc = bid >> 3;
  const int bx = (x & 3) * 4 + (loc & 3);
  const int by = (x >> 2) * 6 + (loc >> 2);
  const int m0 = bx * 256, n0 = by * 256;
  const f16* Ag = A + (size_t)m0 * 1024;
  const f16* Wr = wt + (size_t)n0 * 1024;
  const int zsel = by >> 2, cbs = (by & 3) * 256;
  const float* bias = (zsel == 0 ? bq : zsel == 1 ? bk : bv) + cbs;
  f16* dst = (zsel == 0 ? q : zsel == 1 ? k : v) + cbs;

  f32x4 acc[8][4] = {};

  auto stageH = [&](int par, int mat, int h, int tk) {
    const f16* base = (mat ? Wr : Ag) + (size_t)(h * 128) * 1024 + (tk << 6);
    char* slot = (char*)&L[par * 4 + mat * 2 + h][0];
#pragma unroll
    for (int j = 0; j < 2; j++) {
      int rbase = j * 64 + wid * 8;
      gload16((const char*)&base[(size_t)(rbase + lrow) * 1024] + cb, slot + rbase * 128);
    }
  };
  auto loadA = [&](int par, int h, f16x8 (&af)[8]) {
    const char* S = (const char*)&L[par * 4 + h][0];
#pragma unroll
    for (int mt = 0; mt < 4; mt++) {
      int ra = wm * 64 + mt * 16 + lr;
#pragma unroll
      for (int kh = 0; kh < 2; kh++)
        af[mt * 2 + kh] = *(const f16x8*)(S + ra * 128 + ((kh * 64 + lg * 16) ^ ((lr & 7) << 4)));
    }
  };
  auto loadB = [&](int par, int h, f16x8 (&bf)[4]) {
    const char* S = (const char*)&L[par * 4 + 2 + h][0];
#pragma unroll
    for (int nt = 0; nt < 2; nt++) {
      int rb = wn * 32 + nt * 16 + lr;
#pragma unroll
      for (int kh = 0; kh < 2; kh++)
        bf[nt * 2 + kh] = *(const f16x8*)(S + rb * 128 + ((kh * 64 + lg * 16) ^ ((lr & 7) << 4)));
    }
  };
  auto mfma16 = [&](int mh, int nh, f16x8 (&af)[8], f16x8 (&bf)[4]) {
    __builtin_amdgcn_s_setprio(1);
#pragma unroll
    for (int kh = 0; kh < 2; kh++)
#pragma unroll
      for (int mt = 0; mt < 4; mt++)
#pragma unroll
        for (int nt = 0; nt < 2; nt++)
          acc[mh * 4 + mt][nh * 2 + nt] = MFMA(af[mt * 2 + kh], bf[nt * 2 + kh], acc[mh * 4 + mt][nh * 2 + nt]);
    __builtin_amdgcn_s_setprio(0);
  };

  stageH(0, 0, 0, 0); stageH(0, 1, 0, 0); stageH(0, 1, 1, 0); stageH(0, 0, 1, 0);
  stageH(1, 0, 0, 1); stageH(1, 1, 1, 1); stageH(1, 0, 1, 1);
  asm volatile("s_waitcnt vmcnt(6)" ::: "memory");
  BARRAW();

  f16x8 afA[8], afB[8], bfA[4], bfB[4];
  for (int i = 0; i < 8; i++) {
    const int t2 = 2 * i + 2, t3 = 2 * i + 3;
    const bool pre = (i < 7);
    loadA(0, 0, afA); loadB(0, 0, bfA);
    stageH(1, 1, 0, 2 * i + 1);
    BARRAW(); WAITLGKM0();
    mfma16(0, 0, afA, bfA);
    BARRAW();
    loadB(0, 1, bfB);
    if (pre) stageH(0, 0, 0, t2);
    BARRAW(); WAITLGKM0();
    mfma16(0, 1, afA, bfB);
    BARRAW();
    loadA(0, 1, afB);
    if (pre) stageH(0, 1, 1, t2);
    BARRAW(); WAITLGKM0();
    mfma16(1, 1, afB, bfB);
    BARRAW();
    loadB(0, 0, bfA);
    if (pre) stageH(0, 0, 1, t2);
    asm volatile("s_waitcnt vmcnt(4)" ::: "memory");
    BARRAW(); WAITLGKM0();
    mfma16(1, 0, afB, bfA);
    BARRAW();
    loadA(1, 0, afA); loadB(1, 0, bfA);
    if (pre) stageH(0, 1, 0, t2);
    BARRAW(); WAITLGKM0();
    mfma16(0, 0, afA, bfA);
    BARRAW();
    loadB(1, 1, bfB);
    if (pre) stageH(1, 0, 0, t3);
    BARRAW(); WAITLGKM0();
    mfma16(0, 1, afA, bfB);
    BARRAW();
    loadA(1, 1, afB);
    if (pre) stageH(1, 1, 1, t3);
    BARRAW(); WAITLGKM0();
    mfma16(1, 1, afB, bfB);
    BARRAW();
    loadB(1, 0, bfA);
    if (pre) stageH(1, 0, 1, t3);
    asm volatile("s_waitcnt vmcnt(4)" ::: "memory");
    BARRAW(); WAITLGKM0();
    mfma16(1, 0, afB, bfA);
    BARRAW();
  }

#pragma unroll
  for (int mh = 0; mh < 2; mh++)
#pragma unroll
    for (int mt = 0; mt < 4; mt++)
#pragma unroll
      for (int nh = 0; nh < 2; nh++)
#pragma unroll
        for (int nt = 0; nt < 2; nt++) {
          int col = nh * 128 + wn * 32 + nt * 16 + lr;
          float bcol = bias[col];
#pragma unroll
          for (int e = 0; e < 4; e++) {
            int row = m0 + mh * 128 + wm * 64 + mt * 16 + lg * 4 + e;
            dst[(size_t)row * 1024 + col] = (f16)(acc[mh * 4 + mt][nh * 2 + nt][e] + bcol);
          }
        }
}

// ---------- O-GEMM: 128x128 2-phase (R9) ----------
__global__ __launch_bounds__(256, 2) void k_gemm_o(const f16* __restrict__ A, const f16* __restrict__ Wrows3,
                                                   const float* __restrict__ bo, float* __restrict__ out) {
  __shared__ f16 Al[2][128 * 64];
  __shared__ f16 Bl[2][128 * 64];
  const int t = threadIdx.x;
  const int lane = t & 63, wid = t >> 6;
  const int lr = lane & 15, lg = lane >> 4;
  const int wm = wid >> 1, wn = wid & 1;
  const int lrow = lane >> 3;
  const int cb = (((lane & 7) ^ lrow) << 4);
  const int m0 = blockIdx.x * 128, n0 = blockIdx.y * 128;
  const f16* Wrows = Wrows3 + (size_t)n0 * 1024;
  const float* bias = bo + n0;
  float* of = out + n0;

  f32x4 acc[4][4] = {};

  auto stage = [&](int k0, int bs) {
#pragma unroll
    for (int it = 0; it < 4; it++) {
      int rbase = it * 32 + wid * 8;
      int row = rbase + lrow;
      gload16((const char*)&A[(size_t)(m0 + row) * 1024 + k0] + cb, (char*)&Al[bs][0] + rbase * 128);
      gload16((const char*)&Wrows[(size_t)row * 1024 + k0] + cb, (char*)&Bl[bs][0] + rbase * 128);
    }
  };

  stage(0, 0);
  __syncthreads();
  int cur = 0;
  for (int k0 = 0; k0 < 1024; k0 += 64) {
    if (k0 + 64 < 1024) stage(k0 + 64, cur ^ 1);
    f16x8 af[2][4], bf[2][4];
#pragma unroll
    for (int xx = 0; xx < 4; xx++) {
      int ra = wm * 64 + xx * 16 + lr;
      int rb = wn * 64 + xx * 16 + lr;
#pragma unroll
      for (int kh = 0; kh < 2; kh++) {
        int ca = (kh * 64 + lg * 16) ^ ((lr & 7) << 4);
        af[kh][xx] = *(const f16x8*)((char*)&Al[cur][0] + ra * 128 + ca);
        bf[kh][xx] = *(const f16x8*)((char*)&Bl[cur][0] + rb * 128 + ca);
      }
    }
    __builtin_amdgcn_s_setprio(1);
#pragma unroll
    for (int kh = 0; kh < 2; kh++)
#pragma unroll
      for (int mt = 0; mt < 4; mt++)
#pragma unroll
        for (int nt = 0; nt < 4; nt++)
          acc[mt][nt] = MFMA(af[kh][mt], bf[kh][nt], acc[mt][nt]);
    __builtin_amdgcn_s_setprio(0);
    __syncthreads();
    cur ^= 1;
  }
#pragma unroll
  for (int mt = 0; mt < 4; mt++) {
#pragma unroll
    for (int nt = 0; nt < 4; nt++) {
      int col = wn * 64 + nt * 16 + lr;
      float bcol = bias[col];
#pragma unroll
      for (int e = 0; e < 4; e++) {
        int row = m0 + wm * 64 + mt * 16 + lg * 4 + e;
        of[(size_t)row * 1024 + col] = acc[mt][nt][e] + bcol;
      }
    }
  }
}

// ---------- fused: blocks 0..4095 RMSNorm+RoPE (q AND k); 4096..5119 V transpose ----------
__global__ __launch_bounds__(256) void k_nrv(f16* __restrict__ qh, f16* __restrict__ kh,
                                             const float* __restrict__ gq, const float* __restrict__ gk,
                                             const float* __restrict__ cs, const float* __restrict__ sn,
                                             const f16* __restrict__ vh, f16* __restrict__ vt) {
  __shared__ float smem[2112];                 // vtrans: f16[64][66]; normrope: 8 floats
  int bid = blockIdx.x;
  int t = threadIdx.x;
  if (bid >= 4096) {
    f16* tile = (f16*)smem;                    // [64][66]
    int v = bid - 4096;                        // 0..1023
    int bh = v & 31;
    int t0 = (v >> 5) * 64;
    int b = bh >> 4, h = bh & 15;
    int rr = t >> 3, c8 = (t & 7) * 8;
#pragma unroll
    for (int p = 0; p < 2; p++) {
      int r = p * 32 + rr;
      f16x8 vv = *(const f16x8*)&vh[(size_t)(b * 2048 + t0 + r) * 1024 + h * 64 + c8];
#pragma unroll
      for (int j = 0; j < 8; j++) tile[r * 66 + c8 + j] = vv[j];
    }
    __syncthreads();
#pragma unroll
    for (int p = 0; p < 2; p++) {
      int dh = p * 32 + rr;
      f16x8 o;
#pragma unroll
      for (int j = 0; j < 8; j++) o[j] = tile[(c8 + j) * 66 + dh];
      *(f16x8*)&vt[((size_t)bh * 64 + dh) * 2048 + t0 + c8] = o;
    }
    return;
  }
  int row = bid;
  int c4 = t * 4;
  f16x4 xq = *(const f16x4*)&qh[(size_t)row * 1024 + c4];
  f16x4 xk = *(const f16x4*)&kh[(size_t)row * 1024 + c4];
  float q0 = xq[0], q1 = xq[1], q2 = xq[2], q3 = xq[3];
  float k0 = xk[0], k1 = xk[1], k2 = xk[2], k3 = xk[3];
  float sq = q0 * q0 + q1 * q1 + q2 * q2 + q3 * q3;
  float sk = k0 * k0 + k1 * k1 + k2 * k2 + k3 * k3;
#pragma unroll
  for (int off = 1; off < 64; off <<= 1) { sq += __shfl_xor(sq, off); sk += __shfl_xor(sk, off); }
  float* redq = smem;                          // [4]
  float* redk = smem + 4;                      // [4]
  if ((t & 63) == 0) { redq[t >> 6] = sq; redk[t >> 6] = sk; }
  __syncthreads();
  float invq = rsqrtf((redq[0] + redq[1] + redq[2] + redq[3]) * (1.0f / 1024.0f) + 1e-6f);
  float invk = rsqrtf((redk[0] + redk[1] + redk[2] + redk[3]) * (1.0f / 1024.0f) + 1e-6f);
  int tt = row & 2047;
  float4 cv = *(const float4*)&cs[(size_t)tt * 1024 + c4];
  float4 sv = *(const float4*)&sn[(size_t)tt * 1024 + c4];
  float4 gqv = *(const float4*)&gq[c4];
  float4 gkv = *(const float4*)&gk[c4];
  float a0 = q0 * invq * gqv.x, a1 = q1 * invq * gqv.y, a2 = q2 * invq * gqv.z, a3 = q3 * invq * gqv.w;
  float b0 = k0 * invk * gkv.x, b1 = k1 * invk * gkv.y, b2 = k2 * invk * gkv.z, b3 = k3 * invk * gkv.w;
  f16x4 oq, ok;
  oq[0] = (f16)(a0 * cv.x - a1 * sv.x);
  oq[1] = (f16)(a1 * cv.y + a0 * sv.y);
  oq[2] = (f16)(a2 * cv.z - a3 * sv.z);
  oq[3] = (f16)(a3 * cv.w + a2 * sv.w);
  ok[0] = (f16)(b0 * cv.x - b1 * sv.x);
  ok[1] = (f16)(b1 * cv.y + b0 * sv.y);
  ok[2] = (f16)(b2 * cv.z - b3 * sv.z);
  ok[3] = (f16)(b3 * cv.w + b2 * sv.w);
  *(f16x4*)&qh[(size_t)row * 1024 + c4] = oq;
  *(f16x4*)&kh[(size_t)row * 1024 + c4] = ok;
}

// ---------- flash attention v10: KV-chunk 128, 2x-unrolled loop (fixed LDS bases) ----------
// Manual unroll over buffer parity: all K/V fragment addresses become
// loop-invariant (const LDS base + hoisted lane offset) -> address VALU paid once.
#define ASWZ(row) ((((row) & 3) | (((row) & 8) >> 1)) << 4)
#define VSWZ(row) (((row) & 15) << 4)

__global__ __launch_bounds__(256, 2) void k_attn(const f16* __restrict__ qh, const f16* __restrict__ kh,
                                                 const f16* __restrict__ vt, f16* __restrict__ ao) {
  __shared__ f16 Kl[2][128 * 64];   // 16 KB x2
  __shared__ f16 Vl[2][64 * 128];   // 16 KB x2  -> 64 KB total, 2 blocks/CU
  const int t = threadIdx.x;
  const int lane = t & 63, wid = t >> 6;
  const int lr = lane & 15, lg = lane >> 4;
  const int lgb = lg << 4;
  const int raw = blockIdx.x;
  const int mybh = ((raw & 7) << 2) | ((raw >> 3) & 3);
  const int myq = raw >> 5;
  const int b = mybh >> 4, h = mybh & 15;
  const int q0 = myq * 128 + wid * 32;
  const f16* Qb = qh + ((size_t)(b * 2048 + q0)) * 1024 + h * 64;
  f16x8 qf[2][2];
#pragma unroll
  for (int g = 0; g < 2; g++) {
    qf[g][0] = *(const f16x8*)&Qb[(size_t)(g * 16 + lr) * 1024 + lg * 8];
    qf[g][1] = *(const f16x8*)&Qb[(size_t)(g * 16 + lr) * 1024 + 32 + lg * 8];
  }
  const f16* Kg = kh + ((size_t)b * 2048) * 1024 + h * 64;
  const f16* Vg = vt + ((size_t)mybh) * 64 * 2048;
  const int lrow8 = lane >> 3;
  const int sg8 = (lane & 7) << 4;
  const int lrow16 = lane >> 4;
  const int sg16 = (lane & 15) << 4;
  const float sc = 0.125f * 1.44269504088896340736f;
  float m[2] = {-1e30f, -1e30f};
  f32x4 acc[2][4] = {};
  f32x4 accl[2] = {};
  const f16 ov1 = (lr == 0) ? (f16)1.0f : (f16)0.0f;
  const f16x8 onesf = {ov1, ov1, ov1, ov1, ov1, ov1, ov1, ov1};

  auto stage = [&](int kvo, int bs) {
#pragma unroll
    for (int i = 0; i < 4; i++) {
      int rbK = (i * 4 + wid) * 8;
      int rowK = rbK + lrow8;
      gload16((const char*)(Kg + (size_t)(kvo + rowK) * 1024) + (sg8 ^ ASWZ(rowK)),
              (char*)&Kl[bs][0] + rbK * 128);
      int rbV = (i * 4 + wid) * 4;
      int rowV = rbV + lrow16;
      gload16((const char*)(Vg + (size_t)rowV * 2048 + kvo) + (sg16 ^ VSWZ(rowV)),
              (char*)&Vl[bs][0] + rbV * 256);
    }
  };

  // per-chunk compute; Kb/Vb are compile-time-fixed LDS bases at each call site
  auto chunk = [&](const char* Kb, const char* Vb) {
    f32x4 s[2][8];
    __builtin_amdgcn_s_setprio(1);
#pragma unroll
    for (int ks = 0; ks < 8; ks++) {
      int key = ((lr >> 2) << 3) + (lr & 3) + ((ks & 1) << 2) + (((ks >> 1) & 1) << 5) + ((ks >> 2) << 6);
      int sw = ASWZ(key);
      f16x8 kf0 = *(const f16x8*)(Kb + key * 128 + (lgb ^ sw));
      f16x8 kf1 = *(const f16x8*)(Kb + key * 128 + ((64 + lgb) ^ sw));
#pragma unroll
      for (int g = 0; g < 2; g++) {
        f32x4 z = {};
        z = MFMA(kf0, qf[g][0], z);
        z = MFMA(kf1, qf[g][1], z);
        s[g][ks] = z;
      }
    }
    __builtin_amdgcn_s_setprio(0);

    union U { f16x8 v; f16x2 h[4]; } u[2][4];
#pragma unroll
    for (int g = 0; g < 2; g++) {
      float smax = -1e30f;
#pragma unroll
      for (int ks = 0; ks < 8; ks++)
        smax = fmaxf(fmaxf(fmaxf(smax, s[g][ks][0]), fmaxf(s[g][ks][1], s[g][ks][2])), s[g][ks][3]);
      smax = fmaxf(smax, __shfl_xor(smax, 16));
      smax = fmaxf(smax, __shfl_xor(smax, 32));
      float smc = smax * sc;

      if (!__all(smc - m[g] <= 8.f)) {       // defer-max
        float mn = fmaxf(m[g], smc);
        float al = exp2f(m[g] - mn);
        m[g] = mn;
        float alq[4];
#pragma unroll
        for (int e = 0; e < 4; e++) alq[e] = __shfl(al, lg * 4 + e);
#pragma unroll
        for (int ds = 0; ds < 4; ds++)
#pragma unroll
          for (int e = 0; e < 4; e++) acc[g][ds][e] *= alq[e];
#pragma unroll
        for (int e = 0; e < 4; e++) accl[g][e] *= alq[e];
      }

#pragma unroll
      for (int ks = 0; ks < 8; ks++) {
        float p0 = exp2f(fmaf(s[g][ks][0], sc, -m[g]));
        float p1 = exp2f(fmaf(s[g][ks][1], sc, -m[g]));
        float p2 = exp2f(fmaf(s[g][ks][2], sc, -m[g]));
        float p3 = exp2f(fmaf(s[g][ks][3], sc, -m[g]));
        u[g][ks >> 1].h[(ks & 1) * 2 + 0] = PKRTZ(p0, p1);
        u[g][ks >> 1].h[(ks & 1) * 2 + 1] = PKRTZ(p2, p3);
      }
    }

    __builtin_amdgcn_s_setprio(1);
#pragma unroll
    for (int ds = 0; ds < 4; ds++) {
      int vrow = ds * 16 + lr;
      int sw = VSWZ(vrow);
#pragma unroll
      for (int j = 0; j < 4; j++) {
        f16x8 vf = *(const f16x8*)(Vb + vrow * 256 + ((j * 64 + lgb) ^ sw));
#pragma unroll
        for (int g = 0; g < 2; g++)
          acc[g][ds] = MFMA(u[g][j].v, vf, acc[g][ds]);
      }
    }
#pragma unroll
    for (int g = 0; g < 2; g++)
#pragma unroll
      for (int j = 0; j < 4; j++)
        accl[g] = MFMA(u[g][j].v, onesf, accl[g]);
    __builtin_amdgcn_s_setprio(0);
  };

  stage(0, 0);
  __syncthreads();

  for (int kv0 = 0; kv0 < 2048; kv0 += 256) {
    // chunk in buffer 0; prefetch kv0+128 into buffer 1
    if (kv0 + 128 < 2048) stage(kv0 + 128, 1);
    chunk((const char*)&Kl[0][0], (const char*)&Vl[0][0]);
    __syncthreads();
    // chunk in buffer 1; prefetch kv0+256 into buffer 0
    if (kv0 + 256 < 2048) stage(kv0 + 256, 0);
    chunk((const char*)&Kl[1][0], (const char*)&Vl[1][0]);
    __syncthreads();
  }

#pragma unroll
  for (int g = 0; g < 2; g++) {
#pragma unroll
    for (int e = 0; e < 4; e++) {
      float lf = 1.f / __shfl(accl[g][e], lg << 4);
      size_t row = (size_t)(b * 2048 + q0 + g * 16 + lg * 4 + e);
#pragma unroll
      for (int ds = 0; ds < 4; ds++)
        ao[row * 1024 + h * 64 + ds * 16 + lr] = (f16)(acc[g][ds][e] * lf);
    }
  }
}

extern "C" void kernel_launch(void* const* d_in, const int* in_sizes, int n_in,
                              void* d_out, int out_size, void* d_ws, size_t ws_size,
                              hipStream_t stream) {
  const float* hid  = (const float*)d_in[0];
  const float* cosb = (const float*)d_in[1];
  const float* sinb = (const float*)d_in[2];
  const float* wq = (const float*)d_in[3];
  const float* bq = (const float*)d_in[4];
  const float* wk = (const float*)d_in[5];
  const float* bk = (const float*)d_in[6];
  const float* wv = (const float*)d_in[7];
  const float* bv = (const float*)d_in[8];
  const float* gq = (const float*)d_in[9];
  const float* gk = (const float*)d_in[10];
  const float* wo = (const float*)d_in[11];
  const float* bo = (const float*)d_in[12];
  float* out = (float*)d_out;

  char* ws = (char*)d_ws;
  f16* aH  = (f16*)(ws);                          // 8 MB: hidden fp16 [4096][1024]
  f16* wt  = (f16*)(ws + ((size_t)8 << 20));      // 8 MB: 4 weights transposed [n][k] fp16
  f16* qh  = (f16*)(ws + ((size_t)16 << 20));     // 8 MB
  f16* khb = (f16*)(ws + ((size_t)24 << 20));     // 8 MB
  f16* vhb = (f16*)(ws + ((size_t)32 << 20));     // 8 MB
  f16* vtb = (f16*)(ws + ((size_t)40 << 20));     // 8 MB: V^T [b,h,dh,t]
  f16* ao  = (f16*)(ws + ((size_t)48 << 20));     // 8 MB: attention out [4096][1024]

  k_prep<<<dim3(16, 16, 5), dim3(256), 0, stream>>>(hid, wq, wk, wv, wo, aH, wt);
  k_gemm_qkv<<<dim3(192), dim3(512), 0, stream>>>(aH, wt, bq, bk, bv, qh, khb, vhb);
  k_nrv<<<dim3(5120), dim3(256), 0, stream>>>(qh, khb, gq, gk, cosb, sinb, vhb, vtb);
  k_attn<<<dim3(512), dim3(256), 0, stream>>>(qh, khb, vtb, ao);
  k_gemm_o<<<dim3(32, 8), dim3(256), 0, stream>>>(ao, wt + (size_t)3 * 1024 * 1024, bo, out);
}

// Round 18
// 130.510 us; speedup vs baseline: 1.0258x; 1.0258x over previous
//
#include <hip/hip_runtime.h>

typedef _Float16 f16;
typedef _Float16 f16x8 __attribute__((ext_vector_type(8)));
typedef _Float16 f16x4 __attribute__((ext_vector_type(4)));
typedef _Float16 f16x2 __attribute__((ext_vector_type(2)));
typedef float f32x4 __attribute__((ext_vector_type(4)));

#define MFMA(a, b, c) __builtin_amdgcn_mfma_f32_16x16x32_f16(a, b, c, 0, 0, 0)
#define PKRTZ(a, b) __builtin_bit_cast(f16x2, __builtin_amdgcn_cvt_pkrtz(a, b))
#define BARRAW() do { asm volatile("" ::: "memory"); __builtin_amdgcn_s_barrier(); asm volatile("" ::: "memory"); } while (0)
#define WAITLGKM0() do { asm volatile("s_waitcnt lgkmcnt(0)" ::: "memory"); __builtin_amdgcn_sched_barrier(0); } while (0)

__device__ __forceinline__ void gload16(const void* g, void* l) {
  __builtin_amdgcn_global_load_lds((const __attribute__((address_space(1))) char*)g,
                                   (__attribute__((address_space(3))) char*)l, 16, 0, 0);
}

// B=2, T=2048, D=1024, H=16, DH=64

// ---------- prep: z<4: transpose+convert weight z; z==4: fp32->fp16 hidden ----------
__global__ __launch_bounds__(256) void k_prep(const float* __restrict__ hid,
                                              const float* __restrict__ w0, const float* __restrict__ w1,
                                              const float* __restrict__ w2, const float* __restrict__ w3,
                                              f16* __restrict__ aH, f16* __restrict__ wt) {
  int z = blockIdx.z;
  int t = threadIdx.x;
  if (z == 4) {
    int base = (blockIdx.y * 16 + blockIdx.x) * 256 + t;
#pragma unroll
    for (int j = 0; j < 16; j++) {               // 65536 thr x 16 = 1M float4 = full input
      int i = base + j * 65536;
      float4 v = ((const float4*)hid)[i];
      f16x4 h; h[0] = (f16)v.x; h[1] = (f16)v.y; h[2] = (f16)v.z; h[3] = (f16)v.w;
      ((f16x4*)aH)[i] = h;
    }
    return;
  }
  const float* w = z == 0 ? w0 : z == 1 ? w1 : z == 2 ? w2 : w3;
  f16* dst = wt + (size_t)z * 1024 * 1024;
  __shared__ float tile[64][65];
  int k0 = blockIdx.x * 64, n0 = blockIdx.y * 64;
  int cr = t >> 4, cc = (t & 15) * 4;
#pragma unroll
  for (int p = 0; p < 4; p++) {
    int r = cr + p * 16;
    float4 v = *(const float4*)&w[(size_t)(k0 + r) * 1024 + n0 + cc];
    tile[r][cc + 0] = v.x; tile[r][cc + 1] = v.y; tile[r][cc + 2] = v.z; tile[r][cc + 3] = v.w;
  }
  __syncthreads();
#pragma unroll
  for (int p = 0; p < 4; p++) {
    int nn = cr + p * 16;
    f16x4 h;
    h[0] = (f16)tile[cc + 0][nn]; h[1] = (f16)tile[cc + 1][nn];
    h[2] = (f16)tile[cc + 2][nn]; h[3] = (f16)tile[cc + 3][nn];
    *(f16x4*)&dst[(size_t)(n0 + nn) * 1024 + k0 + cc] = h;
  }
}

// ---------- QKV GEMM: 256x256 tile, BK=64, 8-phase counted-vmcnt pipeline (R9) ----------
__global__ __launch_bounds__(512, 1) void k_gemm_qkv(const f16* __restrict__ A, const f16* __restrict__ wt,
                                                     const float* __restrict__ bq, const float* __restrict__ bk,
                                                     const float* __restrict__ bv,
                                                     f16* __restrict__ q, f16* __restrict__ k, f16* __restrict__ v) {
  __shared__ f16 L[8][128 * 64];
  const int t = threadIdx.x;
  const int lane = t & 63, wid = t >> 6;
  const int lr = lane & 15, lg = lane >> 4;
  const int wm = wid >> 2, wn = wid & 3;
  const int lrow = lane >> 3;
  const int cb = (((lane & 7) ^ lrow) << 4);
  const int bid = blockIdx.x;
  const int x = bid & 7, loc = bid >> 3;
  const int bx = (x & 3) * 4 + (loc & 3);
  const int by = (x >> 2) * 6 + (loc >> 2);
  const int m0 = bx * 256, n0 = by * 256;
  const f16* Ag = A + (size_t)m0 * 1024;
  const f16* Wr = wt + (size_t)n0 * 1024;
  const int zsel = by >> 2, cbs = (by & 3) * 256;
  const float* bias = (zsel == 0 ? bq : zsel == 1 ? bk : bv) + cbs;
  f16* dst = (zsel == 0 ? q : zsel == 1 ? k : v) + cbs;

  f32x4 acc[8][4] = {};

  auto stageH = [&](int par, int mat, int h, int tk) {
    const f16* base = (mat ? Wr : Ag) + (size_t)(h * 128) * 1024 + (tk << 6);
    char* slot = (char*)&L[par * 4 + mat * 2 + h][0];
#pragma unroll
    for (int j = 0; j < 2; j++) {
      int rbase = j * 64 + wid * 8;
      gload16((const char*)&base[(size_t)(rbase + lrow) * 1024] + cb, slot + rbase * 128);
    }
  };
  auto loadA = [&](int par, int h, f16x8 (&af)[8]) {
    const char* S = (const char*)&L[par * 4 + h][0];
#pragma unroll
    for (int mt = 0; mt < 4; mt++) {
      int ra = wm * 64 + mt * 16 + lr;
#pragma unroll
      for (int kh = 0; kh < 2; kh++)
        af[mt * 2 + kh] = *(const f16x8*)(S + ra * 128 + ((kh * 64 + lg * 16) ^ ((lr & 7) << 4)));
    }
  };
  auto loadB = [&](int par, int h, f16x8 (&bf)[4]) {
    const char* S = (const char*)&L[par * 4 + 2 + h][0];
#pragma unroll
    for (int nt = 0; nt < 2; nt++) {
      int rb = wn * 32 + nt * 16 + lr;
#pragma unroll
      for (int kh = 0; kh < 2; kh++)
        bf[nt * 2 + kh] = *(const f16x8*)(S + rb * 128 + ((kh * 64 + lg * 16) ^ ((lr & 7) << 4)));
    }
  };
  auto mfma16 = [&](int mh, int nh, f16x8 (&af)[8], f16x8 (&bf)[4]) {
    __builtin_amdgcn_s_setprio(1);
#pragma unroll
    for (int kh = 0; kh < 2; kh++)
#pragma unroll
      for (int mt = 0; mt < 4; mt++)
#pragma unroll
        for (int nt = 0; nt < 2; nt++)
          acc[mh * 4 + mt][nh * 2 + nt] = MFMA(af[mt * 2 + kh], bf[nt * 2 + kh], acc[mh * 4 + mt][nh * 2 + nt]);
    __builtin_amdgcn_s_setprio(0);
  };

  stageH(0, 0, 0, 0); stageH(0, 1, 0, 0); stageH(0, 1, 1, 0); stageH(0, 0, 1, 0);
  stageH(1, 0, 0, 1); stageH(1, 1, 1, 1); stageH(1, 0, 1, 1);
  asm volatile("s_waitcnt vmcnt(6)" ::: "memory");
  BARRAW();

  f16x8 afA[8], afB[8], bfA[4], bfB[4];
  for (int i = 0; i < 8; i++) {
    const int t2 = 2 * i + 2, t3 = 2 * i + 3;
    const bool pre = (i < 7);
    loadA(0, 0, afA); loadB(0, 0, bfA);
    stageH(1, 1, 0, 2 * i + 1);
    BARRAW(); WAITLGKM0();
    mfma16(0, 0, afA, bfA);
    BARRAW();
    loadB(0, 1, bfB);
    if (pre) stageH(0, 0, 0, t2);
    BARRAW(); WAITLGKM0();
    mfma16(0, 1, afA, bfB);
    BARRAW();
    loadA(0, 1, afB);
    if (pre) stageH(0, 1, 1, t2);
    BARRAW(); WAITLGKM0();
    mfma16(1, 1, afB, bfB);
    BARRAW();
    loadB(0, 0, bfA);
    if (pre) stageH(0, 0, 1, t2);
    asm volatile("s_waitcnt vmcnt(4)" ::: "memory");
    BARRAW(); WAITLGKM0();
    mfma16(1, 0, afB, bfA);
    BARRAW();
    loadA(1, 0, afA); loadB(1, 0, bfA);
    if (pre) stageH(0, 1, 0, t2);
    BARRAW(); WAITLGKM0();
    mfma16(0, 0, afA, bfA);
    BARRAW();
    loadB(1, 1, bfB);
    if (pre) stageH(1, 0, 0, t3);
    BARRAW(); WAITLGKM0();
    mfma16(0, 1, afA, bfB);
    BARRAW();
    loadA(1, 1, afB);
    if (pre) stageH(1, 1, 1, t3);
    BARRAW(); WAITLGKM0();
    mfma16(1, 1, afB, bfB);
    BARRAW();
    loadB(1, 0, bfA);
    if (pre) stageH(1, 0, 1, t3);
    asm volatile("s_waitcnt vmcnt(4)" ::: "memory");
    BARRAW(); WAITLGKM0();
    mfma16(1, 0, afB, bfA);
    BARRAW();
  }

#pragma unroll
  for (int mh = 0; mh < 2; mh++)
#pragma unroll
    for (int mt = 0; mt < 4; mt++)
#pragma unroll
      for (int nh = 0; nh < 2; nh++)
#pragma unroll
        for (int nt = 0; nt < 2; nt++) {
          int col = nh * 128 + wn * 32 + nt * 16 + lr;
          float bcol = bias[col];
#pragma unroll
          for (int e = 0; e < 4; e++) {
            int row = m0 + mh * 128 + wm * 64 + mt * 16 + lg * 4 + e;
            dst[(size_t)row * 1024 + col] = (f16)(acc[mh * 4 + mt][nh * 2 + nt][e] + bcol);
          }
        }
}

// ---------- O-GEMM: 128x128 2-phase (R9) ----------
__global__ __launch_bounds__(256, 2) void k_gemm_o(const f16* __restrict__ A, const f16* __restrict__ Wrows3,
                                                   const float* __restrict__ bo, float* __restrict__ out) {
  __shared__ f16 Al[2][128 * 64];
  __shared__ f16 Bl[2][128 * 64];
  const int t = threadIdx.x;
  const int lane = t & 63, wid = t >> 6;
  const int lr = lane & 15, lg = lane >> 4;
  const int wm = wid >> 1, wn = wid & 1;
  const int lrow = lane >> 3;
  const int cb = (((lane & 7) ^ lrow) << 4);
  const int m0 = blockIdx.x * 128, n0 = blockIdx.y * 128;
  const f16* Wrows = Wrows3 + (size_t)n0 * 1024;
  const float* bias = bo + n0;
  float* of = out + n0;

  f32x4 acc[4][4] = {};

  auto stage = [&](int k0, int bs) {
#pragma unroll
    for (int it = 0; it < 4; it++) {
      int rbase = it * 32 + wid * 8;
      int row = rbase + lrow;
      gload16((const char*)&A[(size_t)(m0 + row) * 1024 + k0] + cb, (char*)&Al[bs][0] + rbase * 128);
      gload16((const char*)&Wrows[(size_t)row * 1024 + k0] + cb, (char*)&Bl[bs][0] + rbase * 128);
    }
  };

  stage(0, 0);
  __syncthreads();
  int cur = 0;
  for (int k0 = 0; k0 < 1024; k0 += 64) {
    if (k0 + 64 < 1024) stage(k0 + 64, cur ^ 1);
    f16x8 af[2][4], bf[2][4];
#pragma unroll
    for (int xx = 0; xx < 4; xx++) {
      int ra = wm * 64 + xx * 16 + lr;
      int rb = wn * 64 + xx * 16 + lr;
#pragma unroll
      for (int kh = 0; kh < 2; kh++) {
        int ca = (kh * 64 + lg * 16) ^ ((lr & 7) << 4);
        af[kh][xx] = *(const f16x8*)((char*)&Al[cur][0] + ra * 128 + ca);
        bf[kh][xx] = *(const f16x8*)((char*)&Bl[cur][0] + rb * 128 + ca);
      }
    }
    __builtin_amdgcn_s_setprio(1);
#pragma unroll
    for (int kh = 0; kh < 2; kh++)
#pragma unroll
      for (int mt = 0; mt < 4; mt++)
#pragma unroll
        for (int nt = 0; nt < 4; nt++)
          acc[mt][nt] = MFMA(af[kh][mt], bf[kh][nt], acc[mt][nt]);
    __builtin_amdgcn_s_setprio(0);
    __syncthreads();
    cur ^= 1;
  }
#pragma unroll
  for (int mt = 0; mt < 4; mt++) {
#pragma unroll
    for (int nt = 0; nt < 4; nt++) {
      int col = wn * 64 + nt * 16 + lr;
      float bcol = bias[col];
#pragma unroll
      for (int e = 0; e < 4; e++) {
        int row = m0 + wm * 64 + mt * 16 + lg * 4 + e;
        of[(size_t)row * 1024 + col] = acc[mt][nt][e] + bcol;
      }
    }
  }
}

// ---------- fused: blocks 0..4095 RMSNorm+RoPE (q AND k); 4096..5119 V transpose ----------
__global__ __launch_bounds__(256) void k_nrv(f16* __restrict__ qh, f16* __restrict__ kh,
                                             const float* __restrict__ gq, const float* __restrict__ gk,
                                             const float* __restrict__ cs, const float* __restrict__ sn,
                                             const f16* __restrict__ vh, f16* __restrict__ vt) {
  __shared__ float smem[2112];                 // vtrans: f16[64][66]; normrope: 8 floats
  int bid = blockIdx.x;
  int t = threadIdx.x;
  if (bid >= 4096) {
    f16* tile = (f16*)smem;                    // [64][66]
    int v = bid - 4096;                        // 0..1023
    int bh = v & 31;
    int t0 = (v >> 5) * 64;
    int b = bh >> 4, h = bh & 15;
    int rr = t >> 3, c8 = (t & 7) * 8;
#pragma unroll
    for (int p = 0; p < 2; p++) {
      int r = p * 32 + rr;
      f16x8 vv = *(const f16x8*)&vh[(size_t)(b * 2048 + t0 + r) * 1024 + h * 64 + c8];
#pragma unroll
      for (int j = 0; j < 8; j++) tile[r * 66 + c8 + j] = vv[j];
    }
    __syncthreads();
#pragma unroll
    for (int p = 0; p < 2; p++) {
      int dh = p * 32 + rr;
      f16x8 o;
#pragma unroll
      for (int j = 0; j < 8; j++) o[j] = tile[(c8 + j) * 66 + dh];
      *(f16x8*)&vt[((size_t)bh * 64 + dh) * 2048 + t0 + c8] = o;
    }
    return;
  }
  int row = bid;
  int c4 = t * 4;
  f16x4 xq = *(const f16x4*)&qh[(size_t)row * 1024 + c4];
  f16x4 xk = *(const f16x4*)&kh[(size_t)row * 1024 + c4];
  float q0 = xq[0], q1 = xq[1], q2 = xq[2], q3 = xq[3];
  float k0 = xk[0], k1 = xk[1], k2 = xk[2], k3 = xk[3];
  float sq = q0 * q0 + q1 * q1 + q2 * q2 + q3 * q3;
  float sk = k0 * k0 + k1 * k1 + k2 * k2 + k3 * k3;
#pragma unroll
  for (int off = 1; off < 64; off <<= 1) { sq += __shfl_xor(sq, off); sk += __shfl_xor(sk, off); }
  float* redq = smem;                          // [4]
  float* redk = smem + 4;                      // [4]
  if ((t & 63) == 0) { redq[t >> 6] = sq; redk[t >> 6] = sk; }
  __syncthreads();
  float invq = rsqrtf((redq[0] + redq[1] + redq[2] + redq[3]) * (1.0f / 1024.0f) + 1e-6f);
  float invk = rsqrtf((redk[0] + redk[1] + redk[2] + redk[3]) * (1.0f / 1024.0f) + 1e-6f);
  int tt = row & 2047;
  float4 cv = *(const float4*)&cs[(size_t)tt * 1024 + c4];
  float4 sv = *(const float4*)&sn[(size_t)tt * 1024 + c4];
  float4 gqv = *(const float4*)&gq[c4];
  float4 gkv = *(const float4*)&gk[c4];
  float a0 = q0 * invq * gqv.x, a1 = q1 * invq * gqv.y, a2 = q2 * invq * gqv.z, a3 = q3 * invq * gqv.w;
  float b0 = k0 * invk * gkv.x, b1 = k1 * invk * gkv.y, b2 = k2 * invk * gkv.z, b3 = k3 * invk * gkv.w;
  f16x4 oq, ok;
  oq[0] = (f16)(a0 * cv.x - a1 * sv.x);
  oq[1] = (f16)(a1 * cv.y + a0 * sv.y);
  oq[2] = (f16)(a2 * cv.z - a3 * sv.z);
  oq[3] = (f16)(a3 * cv.w + a2 * sv.w);
  ok[0] = (f16)(b0 * cv.x - b1 * sv.x);
  ok[1] = (f16)(b1 * cv.y + b0 * sv.y);
  ok[2] = (f16)(b2 * cv.z - b3 * sv.z);
  ok[3] = (f16)(b3 * cv.w + b2 * sv.w);
  *(f16x4*)&qh[(size_t)row * 1024 + c4] = oq;
  *(f16x4*)&kh[(size_t)row * 1024 + c4] = ok;
}

// ---------- flash attention v9: KV-chunk 128, 4-bit V swizzle (conflict-free) ----------
#define ASWZ(row) ((((row) & 3) | (((row) & 8) >> 1)) << 4)
#define VSWZ(row) (((row) & 15) << 4)

__global__ __launch_bounds__(256, 2) void k_attn(const f16* __restrict__ qh, const f16* __restrict__ kh,
                                                 const f16* __restrict__ vt, f16* __restrict__ ao) {
  __shared__ f16 Kl[2][128 * 64];   // 16 KB x2
  __shared__ f16 Vl[2][64 * 128];   // 16 KB x2  -> 64 KB total, 2 blocks/CU
  const int t = threadIdx.x;
  const int lane = t & 63, wid = t >> 6;
  const int lr = lane & 15, lg = lane >> 4;
  const int lgb = lg << 4;
  const int raw = blockIdx.x;
  const int mybh = ((raw & 7) << 2) | ((raw >> 3) & 3);
  const int myq = raw >> 5;
  const int b = mybh >> 4, h = mybh & 15;
  const int q0 = myq * 128 + wid * 32;
  const f16* Qb = qh + ((size_t)(b * 2048 + q0)) * 1024 + h * 64;
  f16x8 qf[2][2];
#pragma unroll
  for (int g = 0; g < 2; g++) {
    qf[g][0] = *(const f16x8*)&Qb[(size_t)(g * 16 + lr) * 1024 + lg * 8];
    qf[g][1] = *(const f16x8*)&Qb[(size_t)(g * 16 + lr) * 1024 + 32 + lg * 8];
  }
  const f16* Kg = kh + ((size_t)b * 2048) * 1024 + h * 64;
  const f16* Vg = vt + ((size_t)mybh) * 64 * 2048;
  const int lrow8 = lane >> 3;
  const int sg8 = (lane & 7) << 4;
  const int lrow16 = lane >> 4;
  const int sg16 = (lane & 15) << 4;
  const float sc = 0.125f * 1.44269504088896340736f;
  float m[2] = {-1e30f, -1e30f};
  f32x4 acc[2][4] = {};
  f32x4 accl[2] = {};
  const f16 ov1 = (lr == 0) ? (f16)1.0f : (f16)0.0f;
  const f16x8 onesf = {ov1, ov1, ov1, ov1, ov1, ov1, ov1, ov1};

  auto stage = [&](int kvo, int bs) {
#pragma unroll
    for (int i = 0; i < 4; i++) {
      int rbK = (i * 4 + wid) * 8;
      int rowK = rbK + lrow8;
      gload16((const char*)(Kg + (size_t)(kvo + rowK) * 1024) + (sg8 ^ ASWZ(rowK)),
              (char*)&Kl[bs][0] + rbK * 128);
      int rbV = (i * 4 + wid) * 4;
      int rowV = rbV + lrow16;
      gload16((const char*)(Vg + (size_t)rowV * 2048 + kvo) + (sg16 ^ VSWZ(rowV)),
              (char*)&Vl[bs][0] + rbV * 256);
    }
  };

  stage(0, 0);
  __syncthreads();
  int cur = 0;

  for (int kv0 = 0; kv0 < 2048; kv0 += 128) {
    if (kv0 + 128 < 2048) stage(kv0 + 128, cur ^ 1);
    const char* Kb = (const char*)&Kl[cur][0];
    const char* Vb = (const char*)&Vl[cur][0];

    f32x4 s[2][8];
    __builtin_amdgcn_s_setprio(1);
#pragma unroll
    for (int ks = 0; ks < 8; ks++) {
      int key = ((lr >> 2) << 3) + (lr & 3) + ((ks & 1) << 2) + (((ks >> 1) & 1) << 5) + ((ks >> 2) << 6);
      int sw = ASWZ(key);
      f16x8 kf0 = *(const f16x8*)(Kb + key * 128 + (lgb ^ sw));
      f16x8 kf1 = *(const f16x8*)(Kb + key * 128 + ((64 + lgb) ^ sw));
#pragma unroll
      for (int g = 0; g < 2; g++) {
        f32x4 z = {};
        z = MFMA(kf0, qf[g][0], z);
        z = MFMA(kf1, qf[g][1], z);
        s[g][ks] = z;
      }
    }
    __builtin_amdgcn_s_setprio(0);

    union U { f16x8 v; f16x2 h[4]; } u[2][4];
#pragma unroll
    for (int g = 0; g < 2; g++) {
      float smax = -1e30f;
#pragma unroll
      for (int ks = 0; ks < 8; ks++)
        smax = fmaxf(fmaxf(fmaxf(smax, s[g][ks][0]), fmaxf(s[g][ks][1], s[g][ks][2])), s[g][ks][3]);
      smax = fmaxf(smax, __shfl_xor(smax, 16));
      smax = fmaxf(smax, __shfl_xor(smax, 32));
      float smc = smax * sc;

      if (!__all(smc - m[g] <= 8.f)) {       // defer-max
        float mn = fmaxf(m[g], smc);
        float al = exp2f(m[g] - mn);
        m[g] = mn;
        float alq[4];
#pragma unroll
        for (int e = 0; e < 4; e++) alq[e] = __shfl(al, lg * 4 + e);
#pragma unroll
        for (int ds = 0; ds < 4; ds++)
#pragma unroll
          for (int e = 0; e < 4; e++) acc[g][ds][e] *= alq[e];
#pragma unroll
        for (int e = 0; e < 4; e++) accl[g][e] *= alq[e];
      }

#pragma unroll
      for (int ks = 0; ks < 8; ks++) {
        float p0 = exp2f(fmaf(s[g][ks][0], sc, -m[g]));
        float p1 = exp2f(fmaf(s[g][ks][1], sc, -m[g]));
        float p2 = exp2f(fmaf(s[g][ks][2], sc, -m[g]));
        float p3 = exp2f(fmaf(s[g][ks][3], sc, -m[g]));
        u[g][ks >> 1].h[(ks & 1) * 2 + 0] = PKRTZ(p0, p1);
        u[g][ks >> 1].h[(ks & 1) * 2 + 1] = PKRTZ(p2, p3);
      }
    }

    __builtin_amdgcn_s_setprio(1);
#pragma unroll
    for (int ds = 0; ds < 4; ds++) {
      int vrow = ds * 16 + lr;
      int sw = VSWZ(vrow);
#pragma unroll
      for (int j = 0; j < 4; j++) {
        f16x8 vf = *(const f16x8*)(Vb + vrow * 256 + ((j * 64 + lgb) ^ sw));
#pragma unroll
        for (int g = 0; g < 2; g++)
          acc[g][ds] = MFMA(u[g][j].v, vf, acc[g][ds]);
      }
    }
#pragma unroll
    for (int g = 0; g < 2; g++)
#pragma unroll
      for (int j = 0; j < 4; j++)
        accl[g] = MFMA(u[g][j].v, onesf, accl[g]);
    __builtin_amdgcn_s_setprio(0);

    __syncthreads();
    cur ^= 1;
  }

#pragma unroll
  for (int g = 0; g < 2; g++) {
#pragma unroll
    for (int e = 0; e < 4; e++) {
      float lf = 1.f / __shfl(accl[g][e], lg << 4);
      size_t row = (size_t)(b * 2048 + q0 + g * 16 + lg * 4 + e);
#pragma unroll
      for (int ds = 0; ds < 4; ds++)
        ao[row * 1024 + h * 64 + ds * 16 + lr] = (f16)(acc[g][ds][e] * lf);
    }
  }
}

extern "C" void kernel_launch(void* const* d_in, const int* in_sizes, int n_in,
                              void* d_out, int out_size, void* d_ws, size_t ws_size,
                              hipStream_t stream) {
  const float* hid  = (const float*)d_in[0];
  const float* cosb = (const float*)d_in[1];
  const float* sinb = (const float*)d_in[2];
  const float* wq = (const float*)d_in[3];
  const float* bq = (const float*)d_in[4];
  const float* wk = (const float*)d_in[5];
  const float* bk = (const float*)d_in[6];
  const float* wv = (const float*)d_in[7];
  const float* bv = (const float*)d_in[8];
  const float* gq = (const float*)d_in[9];
  const float* gk = (const float*)d_in[10];
  const float* wo = (const float*)d_in[11];
  const float* bo = (const float*)d_in[12];
  float* out = (float*)d_out;

  char* ws = (char*)d_ws;
  f16* aH  = (f16*)(ws);                          // 8 MB: hidden fp16 [4096][1024]
  f16* wt  = (f16*)(ws + ((size_t)8 << 20));      // 8 MB: 4 weights transposed [n][k] fp16
  f16* qh  = (f16*)(ws + ((size_t)16 << 20));     // 8 MB
  f16* khb = (f16*)(ws + ((size_t)24 << 20));     // 8 MB
  f16* vhb = (f16*)(ws + ((size_t)32 << 20));     // 8 MB
  f16* vtb = (f16*)(ws + ((size_t)40 << 20));     // 8 MB: V^T [b,h,dh,t]
  f16* ao  = (f16*)(ws + ((size_t)48 << 20));     // 8 MB: attention out [4096][1024]

  k_prep<<<dim3(16, 16, 5), dim3(256), 0, stream>>>(hid, wq, wk, wv, wo, aH, wt);
  k_gemm_qkv<<<dim3(192), dim3(512), 0, stream>>>(aH, wt, bq, bk, bv, qh, khb, vhb);
  k_nrv<<<dim3(5120), dim3(256), 0, stream>>>(qh, khb, gq, gk, cosb, sinb, vhb, vtb);
  k_attn<<<dim3(512), dim3(256), 0, stream>>>(qh, khb, vtb, ao);
  k_gemm_o<<<dim3(32, 8), dim3(256), 0, stream>>>(ao, wt + (size_t)3 * 1024 * 1024, bo, out);
}